// Round 1
// baseline (260.261 us; speedup 1.0000x reference)
//
#include <hip/hip_runtime.h>

#define B_SZ   32
#define LEN    2048
#define DIM    256
#define NST    64
#define OUTD   256
#define CHUNK  64
#define NCHUNK (LEN / CHUNK)     // 32
#define ROWS   (B_SZ * LEN)      // 65536

// ws layout (float offsets)
#define OFF_AT   0               // A_tilde [64][64]
#define OFF_A64  4096            // A_tilde^64 [64][64]
#define OFF_CP   8192            // CP[o][n] = 0.1 * (C @ Minv), [256][64]
#define OFF_S    24576           // chunk-local final states [B][NCHUNK][64]
#define OFF_INST 90112           // chunk carry-in states    [B][NCHUNK][64]
#define OFF_V    155648          // v = x @ B^T [ROWS][64]; H aliases V
#define OFF_H    OFF_V           // scan states g~ [ROWS][64] (overwrites v in-place)
#define WS_FLOATS (OFF_V + (size_t)ROWS * 64)   // 4,349,952 floats = 16.6 MiB

// ---------------------------------------------------------------------------
// global -> LDS direct copy, 16B/lane. lds_base must be wave-uniform; HW adds
// lane*16. Global source is per-lane (pre-swizzled address, m173 pattern).
// ---------------------------------------------------------------------------
__device__ __forceinline__ void gload16(const float* gp, float* lds_base,
                                        int lane_off_f) {
#if __has_builtin(__builtin_amdgcn_global_load_lds)
  (void)lane_off_f;
  __builtin_amdgcn_global_load_lds(
      (const __attribute__((address_space(1))) unsigned int*)gp,
      (__attribute__((address_space(3))) unsigned int*)lds_base, 16, 0, 0);
#else
  float4 tmp = *(const float4*)gp;
  *(float4*)(lds_base + lane_off_f) = tmp;
#endif
}

// dst = a @ b, all [64][68] LDS tiles, 256 threads, 4x4 reg tiles.
__device__ __forceinline__ void mm64(float* dst, const float* a, const float* b,
                                     int t) {
  const int r0 = 4 * (t >> 4), c0 = 4 * (t & 15);
  float acc[4][4] = {};
  for (int k = 0; k < 64; ++k) {
    float4 bv = *(const float4*)(b + k * 68 + c0);
    for (int i = 0; i < 4; ++i) {
      float av = a[(r0 + i) * 68 + k];
      acc[i][0] = fmaf(av, bv.x, acc[i][0]);
      acc[i][1] = fmaf(av, bv.y, acc[i][1]);
      acc[i][2] = fmaf(av, bv.z, acc[i][2]);
      acc[i][3] = fmaf(av, bv.w, acc[i][3]);
    }
  }
  for (int i = 0; i < 4; ++i)
    *(float4*)(dst + (r0 + i) * 68 + c0) =
        make_float4(acc[i][0], acc[i][1], acc[i][2], acc[i][3]);
  __syncthreads();
}

// ---------------------------------------------------------------------------
// K_A fused: block 0 = prep (GJ inverse of M = I + 0.05A -> At = 2*Minv - I;
// A64 = At^64; CP = 0.1 * C @ Minv).  Blocks 1..512 = v[row][m] =
// sum_d x[row][d]*B[m][d], 128-row tile, 8x4 reg tile, swizzled LDS,
// global_load_lds double-buffered staging.
// ---------------------------------------------------------------------------
__global__ __launch_bounds__(256) void k_fused0(const float* __restrict__ A,
                                                const float* __restrict__ Bm,
                                                const float* __restrict__ Cm,
                                                const float* __restrict__ x,
                                                float* __restrict__ ws) {
  __shared__ __align__(16) float sh[13056];    // 52.2 KB
  const int t = threadIdx.x;

  if (blockIdx.x == 0) {
    // ---- carve: Pa/Pb/Pc [64][68]; GJ scratch aliases Pc (dead by then) ----
    float* Pa = sh;
    float* Pb = sh + 4352;
    float* Pc = sh + 8704;
    float* rbM = Pc;             // [2][64]
    float* rbI = Pc + 128;       // [2][64]
    float* cb  = Pc + 256;       // [2][64]

    const int tc = t & 63;       // column owned
    const int tr = t >> 6;       // 0..3; rows 16*tr+i
    float M[16], Iv[16];
    for (int i = 0; i < 16; ++i) {
      int r = 16 * tr + i;
      M[i] = 0.05f * A[r * 64 + tc] + (r == tc ? 1.0f : 0.0f);
      Iv[i] = (r == tc) ? 1.0f : 0.0f;
    }
    if (tr == 0) { rbM[tc] = M[0]; rbI[tc] = Iv[0]; }
    if (tc == 0)
      for (int i = 0; i < 16; ++i) cb[16 * tr + i] = M[i];
    __syncthreads();

    // ---- Gauss-Jordan, no pivoting, 1 barrier/iter ----
#pragma unroll
    for (int k = 0; k < 64; ++k) {
      const int cur = (k & 1) * 64, nxt = ((k + 1) & 1) * 64;
      float rinv = 1.0f / rbM[cur + k];
      float rM = rbM[cur + tc] * rinv;
      float rI = rbI[cur + tc] * rinv;
#pragma unroll
      for (int i = 0; i < 16; ++i) {
        int r = 16 * tr + i;
        if (r == k) { M[i] = rM; Iv[i] = rI; }
        else {
          float f = cb[cur + r];
          M[i] = fmaf(-f, rM, M[i]);
          Iv[i] = fmaf(-f, rI, Iv[i]);
        }
      }
      if (k < 63) {
        if (tr == ((k + 1) >> 4)) {
          rbM[nxt + tc] = M[(k + 1) & 15];
          rbI[nxt + tc] = Iv[(k + 1) & 15];
        }
        if (tc == k + 1)
          for (int i = 0; i < 16; ++i) cb[nxt + 16 * tr + i] = M[i];
      }
      __syncthreads();
    }

    // ---- At = 2*Minv - I  -> ws + Pa; Minv -> Pc (clobbers GJ scratch) ----
    for (int i = 0; i < 16; ++i) {
      int r = 16 * tr + i;
      float at = 2.0f * Iv[i] - (r == tc ? 1.0f : 0.0f);
      ws[OFF_AT + r * 64 + tc] = at;
      Pa[r * 68 + tc] = at;
      Pc[r * 68 + tc] = Iv[i];
    }
    __syncthreads();

    // ---- A64 = At^64 via 6 squarings (Pa <-> Pb), result in Pa ----
    mm64(Pb, Pa, Pa, t);
    mm64(Pa, Pb, Pb, t);
    mm64(Pb, Pa, Pa, t);
    mm64(Pa, Pb, Pb, t);
    mm64(Pb, Pa, Pa, t);
    mm64(Pa, Pb, Pb, t);
    for (int i = 0; i < 16; ++i) {
      int r = 16 * tr + i;
      ws[OFF_A64 + r * 64 + tc] = Pa[r * 68 + tc];
    }

    // ---- CP = 0.1 * C @ Minv : thread t owns output row o = t ----
    {
      const float* Crow = Cm + (size_t)t * 64;
      float4 acc4[16];
      for (int q = 0; q < 16; ++q) acc4[q] = make_float4(0.f, 0.f, 0.f, 0.f);
      for (int k = 0; k < 64; k += 4) {
        float4 c4 = *(const float4*)(Crow + k);
        float ck[4] = {c4.x, c4.y, c4.z, c4.w};
#pragma unroll
        for (int kk = 0; kk < 4; ++kk) {
          const float* mrow = Pc + (k + kk) * 68;
          float c = ck[kk];
#pragma unroll
          for (int q = 0; q < 16; ++q) {
            float4 mv = *(const float4*)(mrow + 4 * q);
            acc4[q].x = fmaf(c, mv.x, acc4[q].x);
            acc4[q].y = fmaf(c, mv.y, acc4[q].y);
            acc4[q].z = fmaf(c, mv.z, acc4[q].z);
            acc4[q].w = fmaf(c, mv.w, acc4[q].w);
          }
        }
      }
      float* cp = ws + OFF_CP + (size_t)t * 64;
      for (int q = 0; q < 16; ++q)
        *(float4*)(cp + 4 * q) =
            make_float4(0.1f * acc4[q].x, 0.1f * acc4[q].y, 0.1f * acc4[q].z,
                        0.1f * acc4[q].w);
    }
  } else {
    // ---- v-GEMM: 128 rows x 64 m per block, K=256 in 8 steps of 32 ----
    // LDS row-major, XOR-swizzled k-slots: lds[row][slot] = g[row][slot^key],
    // key = (row>>3)&7. Staged via global_load_lds with pre-swizzled source.
    float* xs0 = sh;             // [128][32]
    float* xs1 = sh + 4096;
    float* bs0 = sh + 8192;     // [64][32]
    float* bs1 = sh + 10240;
    const int w = t >> 6, lane = t & 63;
    const int ro8 = lane >> 3, kq8 = lane & 7;
    const int rowbase = ((int)blockIdx.x - 1) * 128;

    auto stage = [&](int d0, float* xbuf, float* bbuf) {
      // x tile: 16 chunks (8 rows x 32 f = 1KB); wave w -> chunks 4w..4w+3
#pragma unroll
      for (int c = 0; c < 4; ++c) {
        int q = 4 * w + c;
        const float* gp = x + (size_t)(rowbase + 8 * q + ro8) * 256 + d0 +
                          4 * (kq8 ^ (q & 7));
        gload16(gp, xbuf + q * 256, lane * 4);
      }
      // B tile: 8 chunks; wave w -> chunks 2w..2w+1
#pragma unroll
      for (int c = 0; c < 2; ++c) {
        int q = 2 * w + c;
        const float* gp =
            Bm + (size_t)(8 * q + ro8) * 256 + d0 + 4 * (kq8 ^ q);
        gload16(gp, bbuf + q * 256, lane * 4);
      }
    };

    stage(0, xs0, bs0);
    const int g = lane >> 4, lm = lane & 15;
    const int r0 = 32 * w + 8 * g, m0 = 4 * lm;
    const int ka = 4 * ((4 * w + g) & 7);   // a-read swizzle key (per lane)
    const int kb = 4 * ((lm >> 1) & 7);     // b-read swizzle key
    float acc[8][4] = {};
    float* xc = xs0; float* xn = xs1; float* bc = bs0; float* bn = bs1;
    __syncthreads();

    for (int s = 0; s < 8; ++s) {
      if (s < 7) stage((s + 1) * 32, xn, bn);   // async, lands before barrier
      const float* xa = xc + r0 * 32;
      const float* bb = bc + m0 * 32;
#pragma unroll
      for (int k0 = 0; k0 < 32; k0 += 4) {
        float4 a4[8], b4[4];
#pragma unroll
        for (int i = 0; i < 8; ++i)
          a4[i] = *(const float4*)(xa + i * 32 + (k0 ^ ka));
#pragma unroll
        for (int j = 0; j < 4; ++j)
          b4[j] = *(const float4*)(bb + j * 32 + (k0 ^ kb));
#pragma unroll
        for (int i = 0; i < 8; ++i)
#pragma unroll
          for (int j = 0; j < 4; ++j) {
            acc[i][j] = fmaf(a4[i].x, b4[j].x, acc[i][j]);
            acc[i][j] = fmaf(a4[i].y, b4[j].y, acc[i][j]);
            acc[i][j] = fmaf(a4[i].z, b4[j].z, acc[i][j]);
            acc[i][j] = fmaf(a4[i].w, b4[j].w, acc[i][j]);
          }
      }
      __syncthreads();   // drains vmcnt (next tile ready) + all reads done
      float* tp;
      tp = xc; xc = xn; xn = tp;
      tp = bc; bc = bn; bn = tp;
    }
    float* v = ws + OFF_V;
#pragma unroll
    for (int i = 0; i < 8; ++i)
      *(float4*)(v + (size_t)(rowbase + r0 + i) * 64 + m0) =
          make_float4(acc[i][0], acc[i][1], acc[i][2], acc[i][3]);
  }
}

// ---------------------------------------------------------------------------
// Scan helpers: 64x64 matvec step. areg[j] = M[r][16q+j]; h in LDS.
// ---------------------------------------------------------------------------
__device__ __forceinline__ void load_areg(const float* __restrict__ M, int r,
                                          int q, float areg[16]) {
  const float4* ap = (const float4*)(M + r * 64 + q * 16);
  float4 a0 = ap[0], a1 = ap[1], a2 = ap[2], a3 = ap[3];
  areg[0] = a0.x; areg[1] = a0.y; areg[2] = a0.z; areg[3] = a0.w;
  areg[4] = a1.x; areg[5] = a1.y; areg[6] = a1.z; areg[7] = a1.w;
  areg[8] = a2.x; areg[9] = a2.y; areg[10] = a2.z; areg[11] = a2.w;
  areg[12] = a3.x; areg[13] = a3.y; areg[14] = a3.z; areg[15] = a3.w;
}

__device__ __forceinline__ float matvec_step(const float areg[16],
                                             const float* __restrict__ hcur,
                                             float* __restrict__ part, int r,
                                             int q, int t) {
  float4 ha = *(const float4*)(hcur + q * 16);
  float4 hb = *(const float4*)(hcur + q * 16 + 4);
  float4 hc = *(const float4*)(hcur + q * 16 + 8);
  float4 hd = *(const float4*)(hcur + q * 16 + 12);
  float p0 = fmaf(areg[0], ha.x, fmaf(areg[4], hb.x, fmaf(areg[8], hc.x, areg[12] * hd.x)));
  float p1 = fmaf(areg[1], ha.y, fmaf(areg[5], hb.y, fmaf(areg[9], hc.y, areg[13] * hd.y)));
  float p2 = fmaf(areg[2], ha.z, fmaf(areg[6], hb.z, fmaf(areg[10], hc.z, areg[14] * hd.z)));
  float p3 = fmaf(areg[3], ha.w, fmaf(areg[7], hb.w, fmaf(areg[11], hc.w, areg[15] * hd.w)));
  part[q * 68 + r] = (p0 + p1) + (p2 + p3);
  __syncthreads();
  float s = 0.0f;
  if (t < 64) s = part[t] + part[68 + t] + part[136 + t] + part[204 + t];
  return s;
}

// ---------------------------------------------------------------------------
// K4/K6: chunk-local scan on v directly (g~ state). phase=1: g0=0, emit final
// state to S. phase=3: g0=INST[b][c], emit every g to H (in-place over v).
// ---------------------------------------------------------------------------
__global__ __launch_bounds__(256) void k_chunk(float* __restrict__ ws, int phase) {
  __shared__ __align__(16) float hcur[64];
  __shared__ __align__(16) float part[4 * 68];
  __shared__ __align__(16) float ulds[CHUNK * 64];
  const int t = threadIdx.x;
  const int c = blockIdx.x, b = blockIdx.y;
  const int r = t & 63, q = t >> 6;
  float areg[16];
  load_areg(ws + OFF_AT, r, q, areg);
  const float* u = ws + OFF_V + (size_t)(b * LEN + c * CHUNK) * 64;
  for (int i = 0; i < 4; ++i) {
    int e = 4 * (t + 256 * i);
    *(float4*)(ulds + e) = *(const float4*)(u + e);
  }
  if (t < 64)
    hcur[t] = (phase == 3) ? ws[OFF_INST + (b * NCHUNK + c) * 64 + t] : 0.0f;
  __syncthreads();
  for (int st = 0; st < CHUNK; ++st) {
    float s = matvec_step(areg, hcur, part, r, q, t);
    if (t < 64) {
      float hn = s + ulds[st * 64 + t];
      hcur[t] = hn;
      if (phase == 3)
        ws[OFF_H + (size_t)(b * LEN + c * CHUNK + st) * 64 + t] = hn;
      else if (st == CHUNK - 1)
        ws[OFF_S + (b * NCHUNK + c) * 64 + t] = hn;
    }
    __syncthreads();
  }
}

// ---------------------------------------------------------------------------
// K5: sequential carry combine per batch: INST[b][0]=0,
//     INST[b][c] = A64 @ INST[b][c-1] + S[b][c-1]
// ---------------------------------------------------------------------------
__global__ __launch_bounds__(256) void k_carry(float* __restrict__ ws) {
  __shared__ __align__(16) float hcur[64];
  __shared__ __align__(16) float part[4 * 68];
  __shared__ __align__(16) float slds[NCHUNK * 64];
  const int t = threadIdx.x;
  const int b = blockIdx.x;
  const int r = t & 63, q = t >> 6;
  float areg[16];
  load_areg(ws + OFF_A64, r, q, areg);
  for (int i = 0; i < 2; ++i) {
    int e = 4 * (t + 256 * i);
    *(float4*)(slds + e) = *(const float4*)(ws + OFF_S + b * NCHUNK * 64 + e);
  }
  if (t < 64) {
    hcur[t] = 0.0f;
    ws[OFF_INST + (b * NCHUNK) * 64 + t] = 0.0f;
  }
  __syncthreads();
  for (int c = 1; c < NCHUNK; ++c) {
    float s = matvec_step(areg, hcur, part, r, q, t);
    if (t < 64) {
      float hn = s + slds[(c - 1) * 64 + t];
      hcur[t] = hn;
      ws[OFF_INST + (b * NCHUNK + c) * 64 + t] = hn;
    }
    __syncthreads();
  }
}

// ---------------------------------------------------------------------------
// K7: y[row][o] = sum_n g[row][n] * CP[o][n]. 128 rows x 128 o per block,
// K=64 staged whole, 8x8 reg tile, swizzled LDS via global_load_lds.
// ---------------------------------------------------------------------------
__global__ __launch_bounds__(256) void k_ygemm(const float* __restrict__ ws,
                                               float* __restrict__ y) {
  __shared__ __align__(16) float sh[16384];   // hs[128][64] + cs[128][64]
  float* hs = sh;
  float* cs = sh + 8192;
  const int t = threadIdx.x;
  const int w = t >> 6, lane = t & 63;
  const int rowbase = blockIdx.x * 128;
  const int obase = blockIdx.y * 128;
  const float* H = ws + OFF_H;
  const float* CP = ws + OFF_CP;

  // stage: 32 chunks each (4 rows x 64 f = 1KB); wave w -> chunks 8w..8w+7
  const int ro4 = lane >> 4, kq16 = lane & 15;
#pragma unroll
  for (int c = 0; c < 8; ++c) {
    int q = 8 * w + c;
    int row = 4 * q + ro4;
    int sd = 4 * (kq16 ^ ((row >> 3) & 7));
    gload16(H + (size_t)(rowbase + row) * 64 + sd, hs + q * 256, lane * 4);
    gload16(CP + (size_t)(obase + row) * 64 + sd, cs + q * 256, lane * 4);
  }
  __syncthreads();

  const int g = lane >> 4, lm = lane & 15;
  const int r0 = 32 * w + 8 * g, o0 = 8 * lm;
  const int ka = 4 * ((4 * w + g) & 7);
  const int kb = 4 * (lm & 7);
  const float* ha = hs + r0 * 64;
  const float* cbp = cs + o0 * 64;
  float acc[8][8] = {};
#pragma unroll
  for (int k0 = 0; k0 < 64; k0 += 4) {
    float4 a4[8], b4[8];
#pragma unroll
    for (int i = 0; i < 8; ++i)
      a4[i] = *(const float4*)(ha + i * 64 + (k0 ^ ka));
#pragma unroll
    for (int j = 0; j < 8; ++j)
      b4[j] = *(const float4*)(cbp + j * 64 + (k0 ^ kb));
#pragma unroll
    for (int i = 0; i < 8; ++i)
#pragma unroll
      for (int j = 0; j < 8; ++j) {
        acc[i][j] = fmaf(a4[i].x, b4[j].x, acc[i][j]);
        acc[i][j] = fmaf(a4[i].y, b4[j].y, acc[i][j]);
        acc[i][j] = fmaf(a4[i].z, b4[j].z, acc[i][j]);
        acc[i][j] = fmaf(a4[i].w, b4[j].w, acc[i][j]);
      }
  }
#pragma unroll
  for (int i = 0; i < 8; ++i) {
    float* yp = y + (size_t)(rowbase + r0 + i) * 256 + obase + o0;
    *(float4*)(yp) = make_float4(acc[i][0], acc[i][1], acc[i][2], acc[i][3]);
    *(float4*)(yp + 4) = make_float4(acc[i][4], acc[i][5], acc[i][6], acc[i][7]);
  }
}

// ---------------------------------------------------------------------------
extern "C" void kernel_launch(void* const* d_in, const int* in_sizes, int n_in,
                              void* d_out, int out_size, void* d_ws,
                              size_t ws_size, hipStream_t stream) {
  const float* x = (const float*)d_in[0];
  const float* A = (const float*)d_in[1];
  const float* Bm = (const float*)d_in[2];
  const float* Cm = (const float*)d_in[3];
  float* y = (float*)d_out;
  float* ws = (float*)d_ws;
  if (ws_size < (size_t)WS_FLOATS * sizeof(float)) return;  // scratch too small

  hipLaunchKernelGGL(k_fused0, dim3(1 + ROWS / 128), dim3(256), 0, stream, A,
                     Bm, Cm, x, ws);
  hipLaunchKernelGGL(k_chunk, dim3(NCHUNK, B_SZ), dim3(256), 0, stream, ws, 1);
  hipLaunchKernelGGL(k_carry, dim3(B_SZ), dim3(256), 0, stream, ws);
  hipLaunchKernelGGL(k_chunk, dim3(NCHUNK, B_SZ), dim3(256), 0, stream, ws, 3);
  hipLaunchKernelGGL(k_ygemm, dim3(ROWS / 128, OUTD / 128), dim3(256), 0,
                     stream, ws, y);
}